// Round 10
// baseline (90.298 us; speedup 1.0000x reference)
//
#include <hip/hip_runtime.h>

#define DD 256
#define BB 32
#define NN 8192
#define CC 1000
#define SUBS 32            // blocks per batch in k_main (each block: 256 rows)
#define CACHED_B 16        // b < CACHED_B: plain loads; b >= CACHED_B: NT loads (R7, +1.8us)

typedef float f4 __attribute__((ext_vector_type(4)));

__device__ __forceinline__ f4 ntload(const float* p) {
    return __builtin_nontemporal_load((const f4*)p);
}

// DPP row_ror add: s += rotate_within_16(s, n). CTRL = 0x120|n (row_ror:n).
template <int CTRL>
__device__ __forceinline__ float dpp_ror_add(float s) {
    int r = __builtin_amdgcn_update_dpp(0, __float_as_int(s), CTRL, 0xF, 0xF, true);
    return s + __int_as_float(r);
}
// All-reduce sum across each aligned 16-lane group, result in every lane.
__device__ __forceinline__ float rowsum16(float s) {
    s = dpp_ror_add<0x121>(s);  // row_ror:1
    s = dpp_ror_add<0x122>(s);  // row_ror:2
    s = dpp_ror_add<0x124>(s);  // row_ror:4
    s = dpp_ror_add<0x128>(s);  // row_ror:8
    return s;
}

// ---------------------------------------------------------------------------
// k_prep: 32 blocks (one per batch b). ONE streaming pass over W computes:
//   v1[d]   = sum_k A1[k] W[k,d]      (block 0 writes)
//   c[b]    = sum_d obj[b,d]*(A2·W)[d]
//   o1[b,k] = obj[b,:]·W[k,:] -> x[b*512 + k]   (no k_main dependency; W is
//             already streaming through this block — R9-verified numerics)
// ---------------------------------------------------------------------------
__global__ __launch_bounds__(256) void k_prep(const float* __restrict__ W,
                                              const float* __restrict__ A,
                                              const float* __restrict__ obj,
                                              float* __restrict__ v1,
                                              float* __restrict__ c,
                                              float* __restrict__ x) {
    int b = blockIdx.x, t = threadIdx.x;
    int q    = t >> 6;        // wave = row phase (k ≡ q mod 4)
    int lane = t & 63;
    int cs   = lane * 4;      // column start
    __shared__ float s1[4][DD], s2[4][DD];
    __shared__ float sc[4];
    f4 a1 = {0.f, 0.f, 0.f, 0.f}, a2 = a1;
    f4 ob = *(const f4*)(obj + (size_t)b * DD + cs);
#pragma unroll 4
    for (int k = q; k < DD; k += 4) {
        f4 w = *(const f4*)(W + (size_t)k * DD + cs);
        a1 += A[k] * w;
        a2 += A[DD + k] * w;
        float po = ob.x * w.x + ob.y * w.y + ob.z * w.z + ob.w * w.w;
        po = rowsum16(po);
        po += __shfl_xor(po, 16, 64);
        po += __shfl_xor(po, 32, 64);
        if (lane == 0) x[b * 2 * DD + k] = po;   // o1
    }
    *(f4*)&s1[q][cs] = a1;
    *(f4*)&s2[q][cs] = a2;
    __syncthreads();
    float vv1 = s1[0][t] + s1[1][t] + s1[2][t] + s1[3][t];
    float vv2 = s2[0][t] + s2[1][t] + s2[2][t] + s2[3][t];
    if (b == 0) v1[t] = vv1;
    float p = vv2 * obj[(size_t)b * DD + t];
    p = rowsum16(p);
    p += __shfl_xor(p, 16, 64);
    p += __shfl_xor(p, 32, 64);
    if ((t & 63) == 0) sc[t >> 6] = p;
    __syncthreads();
    if (t == 0) c[b] = sc[0] + sc[1] + sc[2] + sc[3];
}

// ---------------------------------------------------------------------------
// k_main: the 268 MB atom pass — R7 VERBATIM (at the ~6.0 TB/s same-state
// stream ceiling per R6 probeC; within ~5% of the m13 copy ceiling).
// Fusion onto this kernel is closed: R4 (regalloc, 4.5x), R8 (fences, +60us).
// ---------------------------------------------------------------------------
template <bool NT>
__device__ __forceinline__ void atom_loop(const float* __restrict__ p,
                                          const float4& w0, const float4& w1,
                                          const float4& w2, const float4& w3,
                                          float cb,
                                          f4& A0, f4& A1, f4& A2, f4& A3) {
#pragma unroll 4
    for (int g = 0; g < 16; ++g) {
        f4 x0 = NT ? ntload(p)       : *(const f4*)(p);
        f4 x1 = NT ? ntload(p + 64)  : *(const f4*)(p + 64);
        f4 x2 = NT ? ntload(p + 128) : *(const f4*)(p + 128);
        f4 x3 = NT ? ntload(p + 192) : *(const f4*)(p + 192);
        p += 4 * DD;
        float dot = x0.x * w0.x + x0.y * w0.y + x0.z * w0.z + x0.w * w0.w
                  + x1.x * w1.x + x1.y * w1.y + x1.z * w1.z + x1.w * w1.w
                  + x2.x * w2.x + x2.y * w2.y + x2.z * w2.z + x2.w * w2.w
                  + x3.x * w3.x + x3.y * w3.y + x3.z * w3.z + x3.w * w3.w;
        float att = rowsum16(dot) + cb;
        A0 += att * x0;
        A1 += att * x1;
        A2 += att * x2;
        A3 += att * x3;
    }
}

__global__ __launch_bounds__(256, 4) void k_main(const float* __restrict__ atom,
                                                 const float* __restrict__ v1,
                                                 const float* __restrict__ c,
                                                 float* __restrict__ partials) {
    int blk  = blockIdx.x;
    int b    = blk >> 5;
    int sub  = blk & 31;
    int tid  = threadIdx.x;
    int wave = tid >> 6, lane = tid & 63;
    int grp  = lane >> 4, gl = lane & 15;

    __shared__ float sv1[DD];
    __shared__ float tsh[4][DD];
    sv1[tid] = v1[tid];
    __syncthreads();
    float4 w0 = *(const float4*)&sv1[gl * 4];
    float4 w1 = *(const float4*)&sv1[gl * 4 + 64];
    float4 w2 = *(const float4*)&sv1[gl * 4 + 128];
    float4 w3 = *(const float4*)&sv1[gl * 4 + 192];
    float  cb = c[b];

    const float* p = atom + ((size_t)b * NN + (size_t)sub * 256 + wave * 64 + grp) * DD
                   + gl * 4;

    f4 A0 = {0.f, 0.f, 0.f, 0.f}, A1 = A0, A2 = A0, A3 = A0;

    if (b < CACHED_B) {
        atom_loop<false>(p, w0, w1, w2, w3, cb, A0, A1, A2, A3);
    } else {
        atom_loop<true >(p, w0, w1, w2, w3, cb, A0, A1, A2, A3);
    }

#define XRED(v)                              \
    v.x += __shfl_xor(v.x, 16, 64); v.x += __shfl_xor(v.x, 32, 64); \
    v.y += __shfl_xor(v.y, 16, 64); v.y += __shfl_xor(v.y, 32, 64); \
    v.z += __shfl_xor(v.z, 16, 64); v.z += __shfl_xor(v.z, 32, 64); \
    v.w += __shfl_xor(v.w, 16, 64); v.w += __shfl_xor(v.w, 32, 64);
    XRED(A0) XRED(A1) XRED(A2) XRED(A3)
#undef XRED

    if (grp == 0) {
        *(f4*)&tsh[wave][gl * 4]       = A0;
        *(f4*)&tsh[wave][gl * 4 + 64]  = A1;
        *(f4*)&tsh[wave][gl * 4 + 128] = A2;
        *(f4*)&tsh[wave][gl * 4 + 192] = A3;
    }
    __syncthreads();
    partials[(size_t)blk * DD + tid] =
        tsh[0][tid] + tsh[1][tid] + tsh[2][tid] + tsh[3][tid];
}

// ---------------------------------------------------------------------------
// k_mid: grid (32 b x 16 q), 256 threads — R7 structure, msg only (o1 now
// comes from k_prep, so the so/po half of the dot phase is gone).
// ---------------------------------------------------------------------------
__global__ __launch_bounds__(256) void k_mid(const float* __restrict__ partials,
                                             const float* __restrict__ W,
                                             float* __restrict__ x) {
    int b = blockIdx.x >> 4, q = blockIdx.x & 15;
    int t = threadIdx.x;
    __shared__ float tt[DD];

    float s = 0.f;
#pragma unroll 8
    for (int i = 0; i < SUBS; ++i) s += partials[((size_t)(b * SUBS + i)) * DD + t];
    tt[t] = s;
    __syncthreads();

    int kk = t >> 4, cs = t & 15;
    int k  = q * 16 + kk;
    const float4* wr = (const float4*)(W + (size_t)k * DD + cs * 16);
    float p = 0.f;
#pragma unroll
    for (int ii = 0; ii < 4; ++ii) {
        int i = (ii + cs) & 3;  // rotate start -> bank-friendly (R1-verified)
        float4 a  = wr[i];
        float4 xx = *(const float4*)&tt[cs * 16 + i * 4];
        p += a.x * xx.x + a.y * xx.y + a.z * xx.z + a.w * xx.w;
    }
    p = rowsum16(p);
    if (cs == 0) x[b * 2 * DD + DD + k] = p;   // msg
}

// ---------------------------------------------------------------------------
// k_class: grid (4 bg x 63 ch), 256 threads — R7 VERBATIM.
// ---------------------------------------------------------------------------
__global__ __launch_bounds__(256) void k_class(const float* __restrict__ x,
                                               const float* __restrict__ CW,
                                               const float* __restrict__ CB,
                                               float* __restrict__ out) {
    int bg = blockIdx.x / 63, ch = blockIdx.x % 63;
    int t = threadIdx.x;
    __shared__ float xs[8][2 * DD];   // 16 KB

    {
        const f4* src = (const f4*)(x + (size_t)bg * 8 * 2 * DD);
        f4* dst = (f4*)&xs[0][0];
#pragma unroll
        for (int i = 0; i < 4; ++i) dst[t + 256 * i] = src[t + 256 * i];
    }
    __syncthreads();

    int cl = t >> 4, seg = t & 15;
    int j = ch * 16 + cl;
    if (j < CC) {
        const f4* cw = (const f4*)(CW + (size_t)j * 2 * DD + seg * 32);
        float p[8];
#pragma unroll
        for (int bb = 0; bb < 8; ++bb) p[bb] = 0.f;
#pragma unroll
        for (int ii = 0; ii < 8; ++ii) {
            int i = (ii + seg) & 7;
            f4 a = cw[i];
#pragma unroll
            for (int bb = 0; bb < 8; ++bb) {
                f4 v = *(const f4*)&xs[bb][seg * 32 + i * 4];
                p[bb] += a.x * v.x + a.y * v.y + a.z * v.z + a.w * v.w;
            }
        }
#pragma unroll
        for (int bb = 0; bb < 8; ++bb) p[bb] = rowsum16(p[bb]);
        if (seg == 0) {
            float cb = CB[j];
            int b0 = bg * 8;
#pragma unroll
            for (int bb = 0; bb < 8; ++bb)
                out[(size_t)(b0 + bb) * CC + j] = p[bb] + cb;
        }
    }
}

// ---------------------------------------------------------------------------
extern "C" void kernel_launch(void* const* d_in, const int* in_sizes, int n_in,
                              void* d_out, int out_size, void* d_ws, size_t ws_size,
                              hipStream_t stream) {
    const float* atom = (const float*)d_in[0];
    const float* obj  = (const float*)d_in[1];
    const float* W    = (const float*)d_in[2];
    const float* A    = (const float*)d_in[3];
    const float* CW   = (const float*)d_in[4];
    const float* CB   = (const float*)d_in[5];
    float* out = (float*)d_out;

    float* ws = (float*)d_ws;
    float* v1       = ws;                        // 256
    float* c        = ws + 256;                  // 32
    float* x        = ws + 512;                  // 32*512 ([o1, msg] per batch)
    float* partials = x + (size_t)BB * 2 * DD;   // 1024*256 (~1 MB)

    hipLaunchKernelGGL(k_prep,  dim3(BB),        dim3(256), 0, stream, W, A, obj, v1, c, x);
    hipLaunchKernelGGL(k_main,  dim3(BB * SUBS), dim3(256), 0, stream, atom, v1, c, partials);
    hipLaunchKernelGGL(k_mid,   dim3(BB * 16),   dim3(256), 0, stream, partials, W, x);
    hipLaunchKernelGGL(k_class, dim3(4 * 63),    dim3(256), 0, stream, x, CW, CB, out);
}

// Round 11
// 66.862 us; speedup vs baseline: 1.3505x; 1.3505x over previous
//
#include <hip/hip_runtime.h>

#define DD 256
#define BB 32
#define NN 8192
#define CC 1000
#define SUBS 32            // blocks per batch in k_main (each block: 256 rows)
#define CACHED_B 16        // batches b < CACHED_B use plain (L3-allocating) loads;
                           // b >= CACHED_B use NT loads (stream, don't evict).
                           // 16*8192*256*4B = 134 MB pinned half < 256 MB L3.

typedef float f4 __attribute__((ext_vector_type(4)));

__device__ __forceinline__ f4 ntload(const float* p) {
    return __builtin_nontemporal_load((const f4*)p);
}

// DPP row_ror add: s += rotate_within_16(s, n). CTRL = 0x120|n (row_ror:n).
template <int CTRL>
__device__ __forceinline__ float dpp_ror_add(float s) {
    int r = __builtin_amdgcn_update_dpp(0, __float_as_int(s), CTRL, 0xF, 0xF, true);
    return s + __int_as_float(r);
}
// All-reduce sum across each aligned 16-lane group, result in every lane.
__device__ __forceinline__ float rowsum16(float s) {
    s = dpp_ror_add<0x121>(s);  // row_ror:1
    s = dpp_ror_add<0x122>(s);  // row_ror:2
    s = dpp_ror_add<0x124>(s);  // row_ror:4
    s = dpp_ror_add<0x128>(s);  // row_ror:8
    return s;
}

// ---------------------------------------------------------------------------
// k_prep: 32 blocks (one per batch b).  (R7 verbatim — R9/R10 proved that
// adding o1 here with a per-k 64-lane reduction costs +24 us; o1 stays in
// k_mid's 16x16 decomposition where it is ~free.)
//   v1[d] = sum_k A1[k] W[k,d]   (written by block 0)
//   c[b]  = sum_d obj[b,d] * (sum_k A2[k] W[k,d])
// ---------------------------------------------------------------------------
__global__ __launch_bounds__(256) void k_prep(const float* __restrict__ W,
                                              const float* __restrict__ A,
                                              const float* __restrict__ obj,
                                              float* __restrict__ v1,
                                              float* __restrict__ c) {
    int b = blockIdx.x, t = threadIdx.x;
    int q  = t >> 6;
    int cs = (t & 63) * 4;
    __shared__ float s1[4][DD], s2[4][DD];
    __shared__ float sc[4];
    f4 a1 = {0.f, 0.f, 0.f, 0.f}, a2 = a1;
#pragma unroll 8
    for (int k = q; k < DD; k += 4) {
        f4 w = *(const f4*)(W + (size_t)k * DD + cs);
        a1 += A[k] * w;
        a2 += A[DD + k] * w;
    }
    *(f4*)&s1[q][cs] = a1;
    *(f4*)&s2[q][cs] = a2;
    __syncthreads();
    float vv1 = s1[0][t] + s1[1][t] + s1[2][t] + s1[3][t];
    float vv2 = s2[0][t] + s2[1][t] + s2[2][t] + s2[3][t];
    if (b == 0) v1[t] = vv1;
    float p = vv2 * obj[(size_t)b * DD + t];
    p = rowsum16(p);
    p += __shfl_xor(p, 16, 64);
    p += __shfl_xor(p, 32, 64);
    if ((t & 63) == 0) sc[t >> 6] = p;
    __syncthreads();
    if (t == 0) c[b] = sc[0] + sc[1] + sc[2] + sc[3];
}

// ---------------------------------------------------------------------------
// k_main: the 268 MB atom pass, L3-partitioned (R7). At the ~6.0 TB/s
// same-state stream ceiling (R6 probes: this loop <= canonical stream).
// Fusion onto this kernel is closed: R4 (regalloc, 4.5x), R8 (fences, +60us).
// ---------------------------------------------------------------------------
template <bool NT>
__device__ __forceinline__ void atom_loop(const float* __restrict__ p,
                                          const float4& w0, const float4& w1,
                                          const float4& w2, const float4& w3,
                                          float cb,
                                          f4& A0, f4& A1, f4& A2, f4& A3) {
#pragma unroll 4
    for (int g = 0; g < 16; ++g) {
        f4 x0 = NT ? ntload(p)       : *(const f4*)(p);
        f4 x1 = NT ? ntload(p + 64)  : *(const f4*)(p + 64);
        f4 x2 = NT ? ntload(p + 128) : *(const f4*)(p + 128);
        f4 x3 = NT ? ntload(p + 192) : *(const f4*)(p + 192);
        p += 4 * DD;
        float dot = x0.x * w0.x + x0.y * w0.y + x0.z * w0.z + x0.w * w0.w
                  + x1.x * w1.x + x1.y * w1.y + x1.z * w1.z + x1.w * w1.w
                  + x2.x * w2.x + x2.y * w2.y + x2.z * w2.z + x2.w * w2.w
                  + x3.x * w3.x + x3.y * w3.y + x3.z * w3.z + x3.w * w3.w;
        float att = rowsum16(dot) + cb;
        A0 += att * x0;
        A1 += att * x1;
        A2 += att * x2;
        A3 += att * x3;
    }
}

__global__ __launch_bounds__(256, 4) void k_main(const float* __restrict__ atom,
                                                 const float* __restrict__ v1,
                                                 const float* __restrict__ c,
                                                 float* __restrict__ partials) {
    int blk  = blockIdx.x;
    int b    = blk >> 5;
    int sub  = blk & 31;
    int tid  = threadIdx.x;
    int wave = tid >> 6, lane = tid & 63;
    int grp  = lane >> 4, gl = lane & 15;

    __shared__ float sv1[DD];
    __shared__ float tsh[4][DD];
    sv1[tid] = v1[tid];
    __syncthreads();
    float4 w0 = *(const float4*)&sv1[gl * 4];
    float4 w1 = *(const float4*)&sv1[gl * 4 + 64];
    float4 w2 = *(const float4*)&sv1[gl * 4 + 128];
    float4 w3 = *(const float4*)&sv1[gl * 4 + 192];
    float  cb = c[b];

    const float* p = atom + ((size_t)b * NN + (size_t)sub * 256 + wave * 64 + grp) * DD
                   + gl * 4;

    f4 A0 = {0.f, 0.f, 0.f, 0.f}, A1 = A0, A2 = A0, A3 = A0;

    if (b < CACHED_B) {
        atom_loop<false>(p, w0, w1, w2, w3, cb, A0, A1, A2, A3);  // L3-pinned half
    } else {
        atom_loop<true >(p, w0, w1, w2, w3, cb, A0, A1, A2, A3);  // NT stream half
    }

#define XRED(v)                              \
    v.x += __shfl_xor(v.x, 16, 64); v.x += __shfl_xor(v.x, 32, 64); \
    v.y += __shfl_xor(v.y, 16, 64); v.y += __shfl_xor(v.y, 32, 64); \
    v.z += __shfl_xor(v.z, 16, 64); v.z += __shfl_xor(v.z, 32, 64); \
    v.w += __shfl_xor(v.w, 16, 64); v.w += __shfl_xor(v.w, 32, 64);
    XRED(A0) XRED(A1) XRED(A2) XRED(A3)
#undef XRED

    if (grp == 0) {
        *(f4*)&tsh[wave][gl * 4]       = A0;
        *(f4*)&tsh[wave][gl * 4 + 64]  = A1;
        *(f4*)&tsh[wave][gl * 4 + 128] = A2;
        *(f4*)&tsh[wave][gl * 4 + 192] = A3;
    }
    __syncthreads();
    partials[(size_t)blk * DD + tid] =
        tsh[0][tid] + tsh[1][tid] + tsh[2][tid] + tsh[3][tid];
}

// ---------------------------------------------------------------------------
// k_mid: grid (32 b x 16 q), 256 threads.  (R7 verbatim: computes BOTH msg
// and o1 in the 16x16 decomposition — one rowsum16, no 64-lane shfl, o1 is
// ~free here. R9/R10 measured the alternative at +24 us.)
// ---------------------------------------------------------------------------
__global__ __launch_bounds__(256) void k_mid(const float* __restrict__ partials,
                                             const float* __restrict__ W,
                                             const float* __restrict__ obj,
                                             float* __restrict__ x) {
    int b = blockIdx.x >> 4, q = blockIdx.x & 15;
    int t = threadIdx.x;
    __shared__ float tt[DD];
    __shared__ float so[DD];

    float s = 0.f;
#pragma unroll 8
    for (int i = 0; i < SUBS; ++i) s += partials[((size_t)(b * SUBS + i)) * DD + t];
    tt[t] = s;
    so[t] = obj[(size_t)b * DD + t];
    __syncthreads();

    int kk = t >> 4, cs = t & 15;
    int k  = q * 16 + kk;
    const float4* wr = (const float4*)(W + (size_t)k * DD + cs * 16);
    float p = 0.f, po = 0.f;
#pragma unroll
    for (int ii = 0; ii < 4; ++ii) {
        int i = (ii + cs) & 3;
        float4 a  = wr[i];
        float4 xx = *(const float4*)&tt[cs * 16 + i * 4];
        float4 oo = *(const float4*)&so[cs * 16 + i * 4];
        p  += a.x * xx.x + a.y * xx.y + a.z * xx.z + a.w * xx.w;
        po += a.x * oo.x + a.y * oo.y + a.z * oo.z + a.w * oo.w;
    }
    p  = rowsum16(p);
    po = rowsum16(po);
    if (cs == 0) {
        x[b * 2 * DD + DD + k] = p;   // msg
        x[b * 2 * DD + k]      = po;  // o1
    }
}

// ---------------------------------------------------------------------------
// k_class: grid (4 bg x 63 ch), 256 threads — R7 verbatim.
// ---------------------------------------------------------------------------
__global__ __launch_bounds__(256) void k_class(const float* __restrict__ x,
                                               const float* __restrict__ CW,
                                               const float* __restrict__ CB,
                                               float* __restrict__ out) {
    int bg = blockIdx.x / 63, ch = blockIdx.x % 63;
    int t = threadIdx.x;
    __shared__ float xs[8][2 * DD];   // 16 KB

    {
        const f4* src = (const f4*)(x + (size_t)bg * 8 * 2 * DD);
        f4* dst = (f4*)&xs[0][0];
#pragma unroll
        for (int i = 0; i < 4; ++i) dst[t + 256 * i] = src[t + 256 * i];
    }
    __syncthreads();

    int cl = t >> 4, seg = t & 15;
    int j = ch * 16 + cl;
    if (j < CC) {
        const f4* cw = (const f4*)(CW + (size_t)j * 2 * DD + seg * 32);
        float p[8];
#pragma unroll
        for (int bb = 0; bb < 8; ++bb) p[bb] = 0.f;
#pragma unroll
        for (int ii = 0; ii < 8; ++ii) {
            int i = (ii + seg) & 7;
            f4 a = cw[i];
#pragma unroll
            for (int bb = 0; bb < 8; ++bb) {
                f4 v = *(const f4*)&xs[bb][seg * 32 + i * 4];
                p[bb] += a.x * v.x + a.y * v.y + a.z * v.z + a.w * v.w;
            }
        }
#pragma unroll
        for (int bb = 0; bb < 8; ++bb) p[bb] = rowsum16(p[bb]);
        if (seg == 0) {
            float cb = CB[j];
            int b0 = bg * 8;
#pragma unroll
            for (int bb = 0; bb < 8; ++bb)
                out[(size_t)(b0 + bb) * CC + j] = p[bb] + cb;
        }
    }
}

// ---------------------------------------------------------------------------
extern "C" void kernel_launch(void* const* d_in, const int* in_sizes, int n_in,
                              void* d_out, int out_size, void* d_ws, size_t ws_size,
                              hipStream_t stream) {
    const float* atom = (const float*)d_in[0];
    const float* obj  = (const float*)d_in[1];
    const float* W    = (const float*)d_in[2];
    const float* A    = (const float*)d_in[3];
    const float* CW   = (const float*)d_in[4];
    const float* CB   = (const float*)d_in[5];
    float* out = (float*)d_out;

    float* ws = (float*)d_ws;
    float* v1       = ws;                        // 256
    float* c        = ws + 256;                  // 32
    float* x        = ws + 512;                  // 32*512 ([o1, msg] per batch)
    float* partials = x + (size_t)BB * 2 * DD;   // 1024*256 (~1 MB)

    hipLaunchKernelGGL(k_prep,  dim3(BB),        dim3(256), 0, stream, W, A, obj, v1, c);
    hipLaunchKernelGGL(k_main,  dim3(BB * SUBS), dim3(256), 0, stream, atom, v1, c, partials);
    hipLaunchKernelGGL(k_mid,   dim3(BB * 16),   dim3(256), 0, stream, partials, W, obj, x);
    hipLaunchKernelGGL(k_class, dim3(4 * 63),    dim3(256), 0, stream, x, CW, CB, out);
}